// Round 9
// baseline (122.845 us; speedup 1.0000x reference)
//
#include <hip/hip_runtime.h>

#define NN 10000
#define NE 640000
#define DIN 128
#define DOUT 256
#define BN_EPS 1e-5f
#define MPAD 10112    // 79 * 128
#define SLOTS_PN 160  // padded per-node list (max degree ~112 at 12 sigma)
#define NBKT 79       // coarse buckets of 128 nodes (79*128 = 10112)
#define NSB 128       // pass-A sort blocks
#define EPB 5000      // edges per sort block (128*5000 = 640000)

typedef __bf16 bf16x8 __attribute__((ext_vector_type(8)));
typedef float f32x4 __attribute__((ext_vector_type(4)));
typedef float f32x2 __attribute__((ext_vector_type(2)));

__device__ __forceinline__ ushort f2bf(float f) {
    uint u = __float_as_uint(f);
    u += 0x7fffu + ((u >> 16) & 1u);
    return (ushort)(u >> 16);
}
__device__ __forceinline__ uint pk2bf(float a, float b) {
    return (uint)f2bf(a) | ((uint)f2bf(b) << 16);
}
__device__ __forceinline__ uint fp8pk4(float a, float b, float c, float d) {
    int u = __builtin_amdgcn_cvt_pk_fp8_f32(a, b, 0, false);
    u = __builtin_amdgcn_cvt_pk_fp8_f32(c, d, u, true);
    return (uint)u;
}

__device__ __forceinline__ void gload16(const void* g, void* l) {
    __builtin_amdgcn_global_load_lds((const __attribute__((address_space(1))) uint*)g,
                                     (__attribute__((address_space(3))) uint*)l, 16, 0, 0);
}

// ---- fused setup: pass-A edge sort | BN-stats | weight-prep | x->bf16 ----
#define B_SORT NSB                 // [0,128): block-local counting sort
#define B_BN   (B_SORT + 128)      // [128,256): BN partial sums
#define B_PREP (B_BN + 897)        // weight prep (229632 elems)
#define B_CVT  (B_PREP + 1250)     // x -> bf16
__global__ __launch_bounds__(256) void k_setup(const float* __restrict__ x,
                                               const int* __restrict__ src,
                                               const int* __restrict__ tgt,
                                               const float* __restrict__ Wl1, const float* __restrict__ Wr1,
                                               const float* __restrict__ Wl2, const float* __restrict__ Wr2,
                                               const float* __restrict__ Wsr, const float* __restrict__ bl2,
                                               const float* __restrict__ bs,
                                               float* __restrict__ colsum, float* __restrict__ colsumsq,
                                               uint* __restrict__ bsorted, int* __restrict__ boff,
                                               ushort* __restrict__ wcat1, ushort* __restrict__ wcat2,
                                               float* __restrict__ biasc, ushort* __restrict__ cat2) {
    __shared__ __align__(16) uint bufIn[EPB];
    __shared__ __align__(16) uint bufOut[EPB];
    __shared__ int h[NBKT + 1];
    __shared__ int h2[2];
    __shared__ float4 ls[8][32];
    __shared__ float4 lq[8][32];

    int bid = blockIdx.x;
    int tid = threadIdx.x;
    if (bid < B_SORT) {
        // ---- block-local counting sort of 5000 edges by coarse bucket (tgt>>7) ----
        int e0 = bid * EPB;
        for (int i = tid; i < EPB; i += 256)
            bufIn[i] = ((uint)tgt[e0 + i] << 16) | (uint)src[e0 + i];
        if (tid <= NBKT) h[tid] = 0;
        __syncthreads();
        for (int i = tid; i < EPB; i += 256)
            atomicAdd(&h[bufIn[i] >> 23], 1);
        __syncthreads();
        // exclusive scan of h[0..79] across two waves (shfl)
        if (tid < 128) {
            int v = (tid <= NBKT) ? h[tid] : 0;
            int xv = v;
#pragma unroll
            for (int o = 1; o < 64; o <<= 1) {
                int y = __shfl_up(xv, o, 64);
                if ((tid & 63) >= o) xv += y;
            }
            if ((tid & 63) == 63) h2[tid >> 6] = xv;
            __syncthreads();
            int excl = xv - v + ((tid >= 64) ? h2[0] : 0);
            if (tid <= NBKT) {
                h[tid] = excl;
                boff[bid * (NBKT + 1) + tid] = excl;
            }
        } else {
            __syncthreads();
        }
        __syncthreads();
        for (int i = tid; i < EPB; i += 256) {
            uint p = bufIn[i];
            int pos = atomicAdd(&h[p >> 23], 1);
            bufOut[pos] = p;
        }
        __syncthreads();
        const uint4* so = (const uint4*)bufOut;
        uint4* dst = (uint4*)&bsorted[(size_t)bid * EPB];
        for (int i = tid; i < EPB / 4; i += 256) dst[i] = so[i];
    } else if (bid < B_BN) {
        int b2 = bid - B_SORT;
        int lane = tid & 31;
        int rl   = tid >> 5;
        const float4* x4 = (const float4*)x;
        float4 s = make_float4(0, 0, 0, 0);
        float4 q = make_float4(0, 0, 0, 0);
        for (int r = b2 * 8 + rl; r < NN; r += 128 * 8) {
            float4 v = x4[(size_t)r * 32 + lane];
            s.x += v.x; s.y += v.y; s.z += v.z; s.w += v.w;
            q.x += v.x * v.x; q.y += v.y * v.y; q.z += v.z * v.z; q.w += v.w * v.w;
        }
        ls[rl][lane] = s;
        lq[rl][lane] = q;
        __syncthreads();
        if (rl == 0) {
            for (int i = 1; i < 8; ++i) {
                float4 a = ls[i][lane];
                s.x += a.x; s.y += a.y; s.z += a.z; s.w += a.w;
                float4 b = lq[i][lane];
                q.x += b.x; q.y += b.y; q.z += b.z; q.w += b.w;
            }
            atomicAdd(&colsum[lane * 4 + 0], s.x);
            atomicAdd(&colsum[lane * 4 + 1], s.y);
            atomicAdd(&colsum[lane * 4 + 2], s.z);
            atomicAdd(&colsum[lane * 4 + 3], s.w);
            atomicAdd(&colsumsq[lane * 4 + 0], q.x);
            atomicAdd(&colsumsq[lane * 4 + 1], q.y);
            atomicAdd(&colsumsq[lane * 4 + 2], q.z);
            atomicAdd(&colsumsq[lane * 4 + 3], q.w);
        }
    } else if (bid < B_PREP) {
        int i = (bid - B_BN) * 256 + tid;
        if (i < 32768) {                                   // Wr1 -> wcat1[:, 0:128]
            int r = i >> 7, c = i & 127;
            wcat1[r * 256 + c] = f2bf(Wr1[i]);
        } else if (i < 65536) {                            // Wl1 -> wcat1[:, 128:256]
            int j = i - 32768; int r = j >> 7, c = j & 127;
            wcat1[r * 256 + 128 + c] = f2bf(Wl1[j]);
        } else if (i < 131072) {                           // Wr2 -> wcat2[:, 0:256]
            int j = i - 65536; int r = j >> 8, c = j & 255;
            wcat2[r * 640 + c] = f2bf(Wr2[j]);
        } else if (i < 196608) {                           // Wl2 -> wcat2[:, 256:512]
            int j = i - 131072; int r = j >> 8, c = j & 255;
            wcat2[r * 640 + 256 + c] = f2bf(Wl2[j]);
        } else if (i < 229376) {                           // Ws -> wcat2[:, 512:640]
            int j = i - 196608; int r = j >> 7, c = j & 127;
            wcat2[r * 640 + 512 + c] = f2bf(Wsr[j]);
        } else if (i < 229632) {
            int c = i - 229376;
            biasc[c] = bl2[c] + bs[c];
        }
    } else {
        int i = (bid - B_PREP) * 256 + tid;                // x -> bf16 cat2[:, 512:640]
        if (i < NN * 32) {
            int r = i >> 5, c = i & 31;
            float4 v = ((const float4*)x)[i];
            ushort4 o;
            o.x = f2bf(v.x);
            o.y = f2bf(v.y);
            o.z = f2bf(v.z);
            o.w = f2bf(v.w);
            *(ushort4*)&cat2[(size_t)r * 640 + 512 + c * 4] = o;
        }
    }
}

// ---- pass B: per coarse bucket, merge 128 runs -> padded per-node ushort lists ----
__global__ __launch_bounds__(256) void k_sortB(const uint* __restrict__ bsorted,
                                               const int* __restrict__ boff,
                                               ushort* __restrict__ csr,
                                               int* __restrict__ nodecnt) {
    __shared__ __align__(16) ushort pad[128 * SLOTS_PN];  // 40 KB
    __shared__ int cur[128];
    int k = blockIdx.x;
    int tid = threadIdx.x;
    if (tid < 128) cur[tid] = 0;
    __syncthreads();
    int wave = tid >> 6, lane = tid & 63;
    for (int b = wave; b < NSB; b += 4) {
        int j0 = boff[b * (NBKT + 1) + k];
        int j1 = boff[b * (NBKT + 1) + k + 1];
        const uint* run = &bsorted[(size_t)b * EPB];
        for (int j = j0 + lane; j < j1; j += 64) {
            uint p = run[j];
            int l = (p >> 16) & 127;
            int pos = atomicAdd(&cur[l], 1);
            if (pos < SLOTS_PN) pad[l * SLOTS_PN + pos] = (ushort)(p & 0xFFFFu);
        }
    }
    __syncthreads();
    const uint4* ps = (const uint4*)pad;
    uint4* pd = (uint4*)&csr[(size_t)k * 128 * SLOTS_PN];
    for (int i = tid; i < 128 * SLOTS_PN / 8; i += 256) pd[i] = ps[i];
    if (tid < 128) {
        int n = k * 128 + tid;
        if (n < NN) nodecnt[n] = min(cur[tid], SLOTS_PN);
    }
}

// ---- BN apply: xn -> bf16 cat1[:, 0:128] AND fp8 xn8 ----
__global__ __launch_bounds__(256) void k_xn(const float* __restrict__ colsum,
                                            const float* __restrict__ colsumsq,
                                            const float* __restrict__ gamma,
                                            const float* __restrict__ beta,
                                            const float* __restrict__ x,
                                            ushort* __restrict__ cat1,
                                            uint* __restrict__ xn8) {
    int tid = threadIdx.x;
    __shared__ float s_sc[DIN];
    __shared__ float s_sh[DIN];
    if (tid < DIN) {
        float mean = colsum[tid] * (1.0f / NN);
        float var  = colsumsq[tid] * (1.0f / NN) - mean * mean;
        float sc   = gamma[tid] * rsqrtf(var + BN_EPS);
        s_sc[tid] = sc;
        s_sh[tid] = beta[tid] - mean * sc;
    }
    __syncthreads();
    int i = blockIdx.x * 256 + tid;  // float4 units: NN*32
    if (i < NN * 32) {
        int c = i & 31;
        int r = i >> 5;
        float4 v  = ((const float4*)x)[i];
        float4 sc = *(const float4*)&s_sc[c * 4];
        float4 sh = *(const float4*)&s_sh[c * 4];
        float f0 = fmaf(v.x, sc.x, sh.x);
        float f1 = fmaf(v.y, sc.y, sh.y);
        float f2 = fmaf(v.z, sc.z, sh.z);
        float f3 = fmaf(v.w, sc.w, sh.w);
        ushort4 o;
        o.x = f2bf(f0);
        o.y = f2bf(f1);
        o.z = f2bf(f2);
        o.w = f2bf(f3);
        *(ushort4*)&cat1[(size_t)r * 256 + c * 4] = o;
        xn8[i] = fp8pk4(f0, f1, f2, f3);
    }
}

// ---- segment-mean gather from fp8 table: wave-per-node, CHUNKS x SLOTS = 64 lanes ----
template <int CHUNKS, int SLOTS>
__global__ __launch_bounds__(256) void k_agg8(const unsigned char* __restrict__ feat8, int ld16,
                                              const int* __restrict__ nodecnt,
                                              const ushort* __restrict__ csr,
                                              ushort* __restrict__ outp, int outoff8, int outld8) {
    int wave = threadIdx.x >> 6;
    int lane = threadIdx.x & 63;
    int node = blockIdx.x * 4 + wave;
    int chunk = lane % CHUNKS;
    int slot  = lane / CHUNKS;
    int cnt = nodecnt[node];
    const ushort* lst = &csr[(size_t)node * SLOTS_PN];
    const uint4* fp = (const uint4*)feat8;
    float acc[16];
#pragma unroll
    for (int k = 0; k < 16; ++k) acc[k] = 0.f;

#define ACC16(vv)                                                              \
    {                                                                          \
        f32x2 p;                                                               \
        p = __builtin_amdgcn_cvt_pk_f32_fp8((int)vv.x, false); acc[0] += p[0];  acc[1] += p[1];  \
        p = __builtin_amdgcn_cvt_pk_f32_fp8((int)vv.x, true);  acc[2] += p[0];  acc[3] += p[1];  \
        p = __builtin_amdgcn_cvt_pk_f32_fp8((int)vv.y, false); acc[4] += p[0];  acc[5] += p[1];  \
        p = __builtin_amdgcn_cvt_pk_f32_fp8((int)vv.y, true);  acc[6] += p[0];  acc[7] += p[1];  \
        p = __builtin_amdgcn_cvt_pk_f32_fp8((int)vv.z, false); acc[8] += p[0];  acc[9] += p[1];  \
        p = __builtin_amdgcn_cvt_pk_f32_fp8((int)vv.z, true);  acc[10] += p[0]; acc[11] += p[1]; \
        p = __builtin_amdgcn_cvt_pk_f32_fp8((int)vv.w, false); acc[12] += p[0]; acc[13] += p[1]; \
        p = __builtin_amdgcn_cvt_pk_f32_fp8((int)vv.w, true);  acc[14] += p[0]; acc[15] += p[1]; \
    }

    int j = slot;
    for (; j + SLOTS < cnt; j += 2 * SLOTS) {
        int a = lst[j], b = lst[j + SLOTS];
        uint4 va = fp[(size_t)a * ld16 + chunk];
        uint4 vb = fp[(size_t)b * ld16 + chunk];
        ACC16(va);
        ACC16(vb);
    }
    if (j < cnt) {
        int a = lst[j];
        uint4 va = fp[(size_t)a * ld16 + chunk];
        ACC16(va);
    }
#undef ACC16
#pragma unroll
    for (int m = CHUNKS; m < 64; m <<= 1)
#pragma unroll
        for (int k = 0; k < 16; ++k) acc[k] += __shfl_xor(acc[k], m, 64);
    if (slot == 0) {
        float inv = 1.0f / (float)(cnt > 1 ? cnt : 1);
        uint4 o0, o1;
        o0.x = pk2bf(acc[0] * inv, acc[1] * inv);
        o0.y = pk2bf(acc[2] * inv, acc[3] * inv);
        o0.z = pk2bf(acc[4] * inv, acc[5] * inv);
        o0.w = pk2bf(acc[6] * inv, acc[7] * inv);
        o1.x = pk2bf(acc[8] * inv, acc[9] * inv);
        o1.y = pk2bf(acc[10] * inv, acc[11] * inv);
        o1.z = pk2bf(acc[12] * inv, acc[13] * inv);
        o1.w = pk2bf(acc[14] * inv, acc[15] * inv);
        uint4* op = (uint4*)outp;
        op[(size_t)node * outld8 + outoff8 + chunk * 2]     = o0;
        op[(size_t)node * outld8 + outoff8 + chunk * 2 + 1] = o1;
    }
}

// ---- bf16 MFMA GEMM: 128x128 tile, BK=64, 2x2 waves, 16x16x32 ----
template <int K, bool RELU, bool OUTF32, bool OUTF8>
__global__ __launch_bounds__(256) void k_mm(const ushort* __restrict__ A,
                                            const ushort* __restrict__ W,
                                            const float* __restrict__ bias,
                                            float* __restrict__ outf,
                                            ushort* __restrict__ outb, int outld,
                                            unsigned char* __restrict__ out8) {
    __shared__ ushort As[128 * 64];
    __shared__ ushort Bs[128 * 64];
    const int tid = threadIdx.x;
    const int wid = tid >> 6;
    const int lane = tid & 63;
    const int wm = wid >> 1, wn = wid & 1;
    const int m0 = blockIdx.x * 128;
    const int n0 = blockIdx.y * 128;

    const int srow = lane >> 3;
    const int schunk = (lane & 7) ^ srow;
    const int fr = lane & 15;
    const int kg = lane >> 4;
    const int swz = (fr & 7) * 8;
    const int kgo = kg * 8;

    f32x4 acc[4][4];
#pragma unroll
    for (int i = 0; i < 4; ++i)
#pragma unroll
        for (int j = 0; j < 4; ++j) acc[i][j] = (f32x4){0.f, 0.f, 0.f, 0.f};

    for (int kt = 0; kt < K / 64; ++kt) {
#pragma unroll
        for (int i = 0; i < 4; ++i) {
            int rb = i * 32 + wid * 8;
            int r = rb + srow;
            gload16(&A[(size_t)(m0 + r) * K + kt * 64 + schunk * 8], &As[rb * 64]);
            gload16(&W[(size_t)(n0 + r) * K + kt * 64 + schunk * 8], &Bs[rb * 64]);
        }
        __syncthreads();
#pragma unroll
        for (int ks = 0; ks < 2; ++ks) {
            bf16x8 a[4], b[4];
            int koff = ks * 32 + kgo;
#pragma unroll
            for (int f = 0; f < 4; ++f) {
                a[f] = *(const bf16x8*)&As[(wm * 64 + f * 16 + fr) * 64 + (koff ^ swz)];
                b[f] = *(const bf16x8*)&Bs[(wn * 64 + f * 16 + fr) * 64 + (koff ^ swz)];
            }
#pragma unroll
            for (int i = 0; i < 4; ++i)
#pragma unroll
                for (int j = 0; j < 4; ++j)
                    acc[i][j] = __builtin_amdgcn_mfma_f32_16x16x32_bf16(a[i], b[j], acc[i][j], 0, 0, 0);
        }
        __syncthreads();
    }

#pragma unroll
    for (int j = 0; j < 4; ++j) {
        int n = n0 + wn * 64 + j * 16 + fr;
        float bv = bias[n];
#pragma unroll
        for (int i = 0; i < 4; ++i) {
#pragma unroll
            for (int r = 0; r < 4; ++r) {
                int m = m0 + wm * 64 + i * 16 + kg * 4 + r;
                if (m < NN) {
                    float v = acc[i][j][r] + bv;
                    if (RELU) v = fmaxf(v, 0.f);
                    if (OUTF32) outf[(size_t)m * outld + n] = v;
                    else        outb[(size_t)m * outld + n] = f2bf(v);
                    if (OUTF8)
                        out8[(size_t)m * DOUT + n] =
                            (unsigned char)((uint)__builtin_amdgcn_cvt_pk_fp8_f32(v, v, 0, false) & 0xffu);
                }
            }
        }
    }
}

extern "C" void kernel_launch(void* const* d_in, const int* in_sizes, int n_in,
                              void* d_out, int out_size, void* d_ws, size_t ws_size,
                              hipStream_t stream) {
    const float* x     = (const float*)d_in[0];
    const int*   ei    = (const int*)d_in[1];
    const float* gamma = (const float*)d_in[2];
    const float* beta  = (const float*)d_in[3];
    const float* Wl1   = (const float*)d_in[4];
    const float* bl1   = (const float*)d_in[5];
    const float* Wr1   = (const float*)d_in[6];
    const float* Wl2   = (const float*)d_in[7];
    const float* bl2   = (const float*)d_in[8];
    const float* Wr2   = (const float*)d_in[9];
    const float* Wsr   = (const float*)d_in[10];
    const float* bs    = (const float*)d_in[11];
    float* out = (float*)d_out;

    const int* src = ei;
    const int* tgt = ei + NE;

    char* base = (char*)d_ws;
    size_t off = 0;
    auto alloc = [&](size_t bytes) -> void* {
        void* p = base + off;
        off += (bytes + 255) & ~(size_t)255;
        return p;
    };
    float*  colstats = (float*)alloc(2 * DIN * sizeof(float));
    size_t  zbytes   = off;                                 // only colstats zeroed
    float*  colsum   = colstats;
    float*  colsumsq = colstats + DIN;
    float*  biasc    = (float*)alloc(DOUT * sizeof(float));
    int*    nodecnt  = (int*)alloc(NN * sizeof(int));
    int*    boff     = (int*)alloc((size_t)NSB * (NBKT + 1) * sizeof(int)); // 41 KB
    uint*   bsorted  = (uint*)alloc((size_t)NE * sizeof(uint));             // 2.56 MB
    ushort* csr      = (ushort*)alloc((size_t)MPAD * SLOTS_PN * sizeof(ushort)); // 3.2 MB
    ushort* cat1     = (ushort*)alloc((size_t)MPAD * 256 * sizeof(ushort)); // [xn | agg1]
    ushort* cat2     = (ushort*)alloc((size_t)MPAD * 640 * sizeof(ushort)); // [h1 | agg2 | x]
    ushort* wcat1    = (ushort*)alloc(256 * 256 * sizeof(ushort));          // [Wr1 | Wl1]
    ushort* wcat2    = (ushort*)alloc(256 * 640 * sizeof(ushort));          // [Wr2 | Wl2 | Ws]
    uint*   xn8      = (uint*)alloc((size_t)MPAD * 128);                    // fp8 xn
    unsigned char* h8 = (unsigned char*)alloc((size_t)MPAD * 256);          // fp8 h1

    hipMemsetAsync(colstats, 0, zbytes, stream);

    // fused: pass-A sort | BN-stats | weight-prep | x->bf16
    k_setup<<<B_CVT, 256, 0, stream>>>(x, src, tgt, Wl1, Wr1, Wl2, Wr2, Wsr, bl2, bs,
                                       colsum, colsumsq, bsorted, boff, wcat1, wcat2,
                                       biasc, cat2);
    // pass B: merge runs -> padded per-node lists (block-exclusive coalesced writes)
    k_sortB<<<NBKT, 256, 0, stream>>>(bsorted, boff, csr, nodecnt);
    // BN apply (bf16 + fp8)
    k_xn<<<(NN * 32 + 255) / 256, 256, 0, stream>>>(colsum, colsumsq, gamma, beta, x, cat1, xn8);

    dim3 ggrid((MPAD / 128), 2);

    // conv1: h1 = relu([xn|agg1] @ [Wr1|Wl1]^T + bl1) -> bf16 cat2 cols 0:256 + fp8 h8
    k_agg8<8, 8><<<NN / 4, 256, 0, stream>>>((const unsigned char*)xn8, 8, nodecnt, csr,
                                             cat1, 16, 32);
    k_mm<256, true, false, true><<<ggrid, 256, 0, stream>>>(cat1, wcat1, bl1, nullptr,
                                                            cat2, 640, h8);

    // conv2 + residual: out = [h1|agg2|x] @ [Wr2|Wl2|Ws]^T + (bl2+bs)  (f32)
    k_agg8<16, 4><<<NN / 4, 256, 0, stream>>>(h8, 16, nodecnt, csr, cat2, 32, 80);
    k_mm<640, false, true, false><<<ggrid, 256, 0, stream>>>(cat2, wcat2, biasc, out,
                                                             nullptr, 256, nullptr);
}

// Round 10
// 106.252 us; speedup vs baseline: 1.1562x; 1.1562x over previous
//
#include <hip/hip_runtime.h>

#define NN 10000
#define NE 640000
#define DIN 128
#define DOUT 256
#define BN_EPS 1e-5f
#define MPAD 10112    // 79 * 128
#define SLOTS_PN 160  // padded per-node list (max degree ~112 at 12 sigma)
#define NBKT 79       // coarse buckets of 128 nodes (79*128 = 10112)
#define NSB 128       // pass-A sort blocks
#define EPB 5000      // edges per sort block (128*5000 = 640000)

typedef __bf16 bf16x8 __attribute__((ext_vector_type(8)));
typedef float f32x4 __attribute__((ext_vector_type(4)));
typedef float f32x2 __attribute__((ext_vector_type(2)));

__device__ __forceinline__ ushort f2bf(float f) {
    uint u = __float_as_uint(f);
    u += 0x7fffu + ((u >> 16) & 1u);
    return (ushort)(u >> 16);
}
__device__ __forceinline__ uint pk2bf(float a, float b) {
    return (uint)f2bf(a) | ((uint)f2bf(b) << 16);
}
__device__ __forceinline__ uint fp8pk4(float a, float b, float c, float d) {
    int u = __builtin_amdgcn_cvt_pk_fp8_f32(a, b, 0, false);
    u = __builtin_amdgcn_cvt_pk_fp8_f32(c, d, u, true);
    return (uint)u;
}

__device__ __forceinline__ void gload16(const void* g, void* l) {
    __builtin_amdgcn_global_load_lds((const __attribute__((address_space(1))) uint*)g,
                                     (__attribute__((address_space(3))) uint*)l, 16, 0, 0);
}

// ---- k1: pass-A edge sort | BN partial sums (no atomics) | x -> bf16 x2 + fp8 ----
#define B_SORT NSB              // [0,128): block-local counting sort
#define B_BN   (B_SORT + 128)   // [128,256): BN partials -> colpart[b][256]
#define B_CVT  (B_BN + 1250)    // [256,1506): x -> cat1[:,0:128] bf16, cat2[:,512:640] bf16, x8 fp8
__global__ __launch_bounds__(256) void k_setup(const float* __restrict__ x,
                                               const int* __restrict__ src,
                                               const int* __restrict__ tgt,
                                               float* __restrict__ colpart,
                                               uint* __restrict__ bsorted, int* __restrict__ boff,
                                               ushort* __restrict__ cat1, ushort* __restrict__ cat2,
                                               uint* __restrict__ x8) {
    __shared__ __align__(16) uint bufIn[EPB];
    __shared__ __align__(16) uint bufOut[EPB];
    __shared__ int h[NBKT + 1];
    __shared__ int h2[2];
    __shared__ float4 ls[8][32];
    __shared__ float4 lq[8][32];

    int bid = blockIdx.x;
    int tid = threadIdx.x;
    if (bid < B_SORT) {
        // block-local counting sort of 5000 edges by coarse bucket (tgt>>7)
        int e0 = bid * EPB;
        for (int i = tid; i < EPB; i += 256)
            bufIn[i] = ((uint)tgt[e0 + i] << 16) | (uint)src[e0 + i];
        if (tid <= NBKT) h[tid] = 0;
        __syncthreads();
        for (int i = tid; i < EPB; i += 256)
            atomicAdd(&h[bufIn[i] >> 23], 1);
        __syncthreads();
        if (tid < 128) {
            int v = (tid <= NBKT) ? h[tid] : 0;
            int xv = v;
#pragma unroll
            for (int o = 1; o < 64; o <<= 1) {
                int y = __shfl_up(xv, o, 64);
                if ((tid & 63) >= o) xv += y;
            }
            if ((tid & 63) == 63) h2[tid >> 6] = xv;
            __syncthreads();
            int excl = xv - v + ((tid >= 64) ? h2[0] : 0);
            if (tid <= NBKT) {
                h[tid] = excl;
                boff[bid * (NBKT + 1) + tid] = excl;
            }
        } else {
            __syncthreads();
        }
        __syncthreads();
        for (int i = tid; i < EPB; i += 256) {
            uint p = bufIn[i];
            int pos = atomicAdd(&h[p >> 23], 1);
            bufOut[pos] = p;
        }
        __syncthreads();
        const uint4* so = (const uint4*)bufOut;
        uint4* dst = (uint4*)&bsorted[(size_t)bid * EPB];
        for (int i = tid; i < EPB / 4; i += 256) dst[i] = so[i];
    } else if (bid < B_BN) {
        int b2 = bid - B_SORT;
        int lane = tid & 31;
        int rl   = tid >> 5;
        const float4* x4 = (const float4*)x;
        float4 s = make_float4(0, 0, 0, 0);
        float4 q = make_float4(0, 0, 0, 0);
        for (int r = b2 * 8 + rl; r < NN; r += 128 * 8) {
            float4 v = x4[(size_t)r * 32 + lane];
            s.x += v.x; s.y += v.y; s.z += v.z; s.w += v.w;
            q.x += v.x * v.x; q.y += v.y * v.y; q.z += v.z * v.z; q.w += v.w * v.w;
        }
        ls[rl][lane] = s;
        lq[rl][lane] = q;
        __syncthreads();
        if (rl == 0) {
            for (int i = 1; i < 8; ++i) {
                float4 a = ls[i][lane];
                s.x += a.x; s.y += a.y; s.z += a.z; s.w += a.w;
                float4 b = lq[i][lane];
                q.x += b.x; q.y += b.y; q.z += b.z; q.w += b.w;
            }
            ((float4*)&colpart[b2 * 256])[lane] = s;        // cols 0:128 = sums
            ((float4*)&colpart[b2 * 256 + 128])[lane] = q;  // cols 128:256 = sumsq
        }
    } else {
        int i = (bid - B_BN) * 256 + tid;  // float4 units: NN*32
        if (i < NN * 32) {
            int r = i >> 5, c = i & 31;
            float4 v = ((const float4*)x)[i];
            ushort4 o;
            o.x = f2bf(v.x);
            o.y = f2bf(v.y);
            o.z = f2bf(v.z);
            o.w = f2bf(v.w);
            *(ushort4*)&cat1[(size_t)r * 256 + c * 4] = o;          // cat1[:,0:128]
            *(ushort4*)&cat2[(size_t)r * 640 + 512 + c * 4] = o;    // cat2[:,512:640]
            x8[i] = fp8pk4(v.x, v.y, v.z, v.w);                      // fp8 raw x
        }
    }
}

// ---- k2: sortB (csr build) | BN-folded wcat1 | wcat2 | bias fold ----
#define P_SB 79
#define P_W1 (P_SB + 256)   // 65536 elems: Wr1|Wl1 scaled
#define P_W2 (P_W1 + 640)   // 163840 elems: Wr2|Wl2|Ws
#define P_BIAS P_W2         // block P_W2: bias1 + biasc  (grid = P_W2+1)
__global__ __launch_bounds__(256) void k_prep2(const uint* __restrict__ bsorted,
                                               const int* __restrict__ boff,
                                               ushort* __restrict__ csr,
                                               int* __restrict__ nodecnt,
                                               const float* __restrict__ colpart,
                                               const float* __restrict__ gamma,
                                               const float* __restrict__ beta,
                                               const float* __restrict__ Wl1, const float* __restrict__ Wr1,
                                               const float* __restrict__ Wl2, const float* __restrict__ Wr2,
                                               const float* __restrict__ Wsr,
                                               const float* __restrict__ bl1, const float* __restrict__ bl2,
                                               const float* __restrict__ bs,
                                               ushort* __restrict__ wcat1, ushort* __restrict__ wcat2,
                                               float* __restrict__ bias1, float* __restrict__ biasc) {
    __shared__ __align__(16) ushort pad[128 * SLOTS_PN];  // 40 KB
    __shared__ int cur[128];
    __shared__ float s_sc[DIN];
    __shared__ float s_sh[DIN];

    int bid = blockIdx.x;
    int tid = threadIdx.x;
    if (bid < P_SB) {
        // merge 128 sorted runs for bucket bid -> padded per-node ushort lists
        int k = bid;
        if (tid < 128) cur[tid] = 0;
        __syncthreads();
        int wave = tid >> 6, lane = tid & 63;
        for (int b = wave; b < NSB; b += 4) {
            int j0 = boff[b * (NBKT + 1) + k];
            int j1 = boff[b * (NBKT + 1) + k + 1];
            const uint* run = &bsorted[(size_t)b * EPB];
            for (int j = j0 + lane; j < j1; j += 64) {
                uint p = run[j];
                int l = (p >> 16) & 127;
                int pos = atomicAdd(&cur[l], 1);
                if (pos < SLOTS_PN) pad[l * SLOTS_PN + pos] = (ushort)(p & 0xFFFFu);
            }
        }
        __syncthreads();
        const uint4* ps = (const uint4*)pad;
        uint4* pd = (uint4*)&csr[(size_t)k * 128 * SLOTS_PN];
        for (int i = tid; i < 128 * SLOTS_PN / 8; i += 256) pd[i] = ps[i];
        if (tid < 128) {
            int n = k * 128 + tid;
            if (n < NN) nodecnt[n] = min(cur[tid], SLOTS_PN);
        }
    } else if (bid < P_W1) {
        // self-reduce colpart -> scale, then wcat1 = [Wr1|Wl1] * scale[k]
        if (tid < DIN) {
            float s = 0.f, q = 0.f;
            for (int b = 0; b < 128; ++b) {
                s += colpart[b * 256 + tid];
                q += colpart[b * 256 + 128 + tid];
            }
            float mean = s * (1.0f / NN);
            float var  = q * (1.0f / NN) - mean * mean;
            s_sc[tid] = gamma[tid] * rsqrtf(var + BN_EPS);
        }
        __syncthreads();
        int i = (bid - P_SB) * 256 + tid;  // [0, 65536)
        if (i < 32768) {                                   // Wr1 -> wcat1[:, 0:128]
            int r = i >> 7, c = i & 127;
            wcat1[r * 256 + c] = f2bf(Wr1[i] * s_sc[c]);
        } else {                                           // Wl1 -> wcat1[:, 128:256]
            int j = i - 32768; int r = j >> 7, c = j & 127;
            wcat1[r * 256 + 128 + c] = f2bf(Wl1[j] * s_sc[c]);
        }
    } else if (bid < P_W2) {
        int i = (bid - P_W1) * 256 + tid;  // [0, 163840)
        if (i < 65536) {                                   // Wr2 -> wcat2[:, 0:256]
            int r = i >> 8, c = i & 255;
            wcat2[r * 640 + c] = f2bf(Wr2[i]);
        } else if (i < 131072) {                           // Wl2 -> wcat2[:, 256:512]
            int j = i - 65536; int r = j >> 8, c = j & 255;
            wcat2[r * 640 + 256 + c] = f2bf(Wl2[j]);
        } else {                                           // Ws -> wcat2[:, 512:640]
            int j = i - 131072; int r = j >> 7, c = j & 127;
            wcat2[r * 640 + 512 + c] = f2bf(Wsr[j]);
        }
    } else {
        // bias fold: bias1 = bl1 + (Wr1+Wl1) @ shift ; biasc = bl2 + bs
        if (tid < DIN) {
            float s = 0.f, q = 0.f;
            for (int b = 0; b < 128; ++b) {
                s += colpart[b * 256 + tid];
                q += colpart[b * 256 + 128 + tid];
            }
            float mean = s * (1.0f / NN);
            float var  = q * (1.0f / NN) - mean * mean;
            float sc   = gamma[tid] * rsqrtf(var + BN_EPS);
            s_sh[tid]  = beta[tid] - mean * sc;
        }
        __syncthreads();
        int n = tid;  // 256 output cols
        float acc = bl1[n];
        for (int k = 0; k < DIN; ++k)
            acc += (Wr1[n * DIN + k] + Wl1[n * DIN + k]) * s_sh[k];
        bias1[n] = acc;
        biasc[n] = bl2[n] + bs[n];
    }
}

// ---- segment-mean gather from fp8 table: wave-per-node, CHUNKS x SLOTS = 64 lanes ----
template <int CHUNKS, int SLOTS>
__global__ __launch_bounds__(256) void k_agg8(const unsigned char* __restrict__ feat8, int ld16,
                                              const int* __restrict__ nodecnt,
                                              const ushort* __restrict__ csr,
                                              ushort* __restrict__ outp, int outoff8, int outld8) {
    int wave = threadIdx.x >> 6;
    int lane = threadIdx.x & 63;
    int node = blockIdx.x * 4 + wave;
    int chunk = lane % CHUNKS;
    int slot  = lane / CHUNKS;
    int cnt = nodecnt[node];
    const ushort* lst = &csr[(size_t)node * SLOTS_PN];
    const uint4* fp = (const uint4*)feat8;
    float acc[16];
#pragma unroll
    for (int k = 0; k < 16; ++k) acc[k] = 0.f;

#define ACC16(vv)                                                              \
    {                                                                          \
        f32x2 p;                                                               \
        p = __builtin_amdgcn_cvt_pk_f32_fp8((int)vv.x, false); acc[0] += p[0];  acc[1] += p[1];  \
        p = __builtin_amdgcn_cvt_pk_f32_fp8((int)vv.x, true);  acc[2] += p[0];  acc[3] += p[1];  \
        p = __builtin_amdgcn_cvt_pk_f32_fp8((int)vv.y, false); acc[4] += p[0];  acc[5] += p[1];  \
        p = __builtin_amdgcn_cvt_pk_f32_fp8((int)vv.y, true);  acc[6] += p[0];  acc[7] += p[1];  \
        p = __builtin_amdgcn_cvt_pk_f32_fp8((int)vv.z, false); acc[8] += p[0];  acc[9] += p[1];  \
        p = __builtin_amdgcn_cvt_pk_f32_fp8((int)vv.z, true);  acc[10] += p[0]; acc[11] += p[1]; \
        p = __builtin_amdgcn_cvt_pk_f32_fp8((int)vv.w, false); acc[12] += p[0]; acc[13] += p[1]; \
        p = __builtin_amdgcn_cvt_pk_f32_fp8((int)vv.w, true);  acc[14] += p[0]; acc[15] += p[1]; \
    }

    int j = slot;
    for (; j + SLOTS < cnt; j += 2 * SLOTS) {
        int a = lst[j], b = lst[j + SLOTS];
        uint4 va = fp[(size_t)a * ld16 + chunk];
        uint4 vb = fp[(size_t)b * ld16 + chunk];
        ACC16(va);
        ACC16(vb);
    }
    if (j < cnt) {
        int a = lst[j];
        uint4 va = fp[(size_t)a * ld16 + chunk];
        ACC16(va);
    }
#undef ACC16
#pragma unroll
    for (int m = CHUNKS; m < 64; m <<= 1)
#pragma unroll
        for (int k = 0; k < 16; ++k) acc[k] += __shfl_xor(acc[k], m, 64);
    if (slot == 0) {
        float inv = 1.0f / (float)(cnt > 1 ? cnt : 1);
        uint4 o0, o1;
        o0.x = pk2bf(acc[0] * inv, acc[1] * inv);
        o0.y = pk2bf(acc[2] * inv, acc[3] * inv);
        o0.z = pk2bf(acc[4] * inv, acc[5] * inv);
        o0.w = pk2bf(acc[6] * inv, acc[7] * inv);
        o1.x = pk2bf(acc[8] * inv, acc[9] * inv);
        o1.y = pk2bf(acc[10] * inv, acc[11] * inv);
        o1.z = pk2bf(acc[12] * inv, acc[13] * inv);
        o1.w = pk2bf(acc[14] * inv, acc[15] * inv);
        uint4* op = (uint4*)outp;
        op[(size_t)node * outld8 + outoff8 + chunk * 2]     = o0;
        op[(size_t)node * outld8 + outoff8 + chunk * 2 + 1] = o1;
    }
}

// ---- bf16 MFMA GEMM: 128x128 tile, BK=64, 2x2 waves, 16x16x32 ----
template <int K, bool RELU, bool OUTF32, bool OUTF8>
__global__ __launch_bounds__(256) void k_mm(const ushort* __restrict__ A,
                                            const ushort* __restrict__ W,
                                            const float* __restrict__ bias,
                                            float* __restrict__ outf,
                                            ushort* __restrict__ outb, int outld,
                                            unsigned char* __restrict__ out8) {
    __shared__ ushort As[128 * 64];
    __shared__ ushort Bs[128 * 64];
    const int tid = threadIdx.x;
    const int wid = tid >> 6;
    const int lane = tid & 63;
    const int wm = wid >> 1, wn = wid & 1;
    const int m0 = blockIdx.x * 128;
    const int n0 = blockIdx.y * 128;

    const int srow = lane >> 3;
    const int schunk = (lane & 7) ^ srow;
    const int fr = lane & 15;
    const int kg = lane >> 4;
    const int swz = (fr & 7) * 8;
    const int kgo = kg * 8;

    f32x4 acc[4][4];
#pragma unroll
    for (int i = 0; i < 4; ++i)
#pragma unroll
        for (int j = 0; j < 4; ++j) acc[i][j] = (f32x4){0.f, 0.f, 0.f, 0.f};

    for (int kt = 0; kt < K / 64; ++kt) {
#pragma unroll
        for (int i = 0; i < 4; ++i) {
            int rb = i * 32 + wid * 8;
            int r = rb + srow;
            gload16(&A[(size_t)(m0 + r) * K + kt * 64 + schunk * 8], &As[rb * 64]);
            gload16(&W[(size_t)(n0 + r) * K + kt * 64 + schunk * 8], &Bs[rb * 64]);
        }
        __syncthreads();
#pragma unroll
        for (int ks = 0; ks < 2; ++ks) {
            bf16x8 a[4], b[4];
            int koff = ks * 32 + kgo;
#pragma unroll
            for (int f = 0; f < 4; ++f) {
                a[f] = *(const bf16x8*)&As[(wm * 64 + f * 16 + fr) * 64 + (koff ^ swz)];
                b[f] = *(const bf16x8*)&Bs[(wn * 64 + f * 16 + fr) * 64 + (koff ^ swz)];
            }
#pragma unroll
            for (int i = 0; i < 4; ++i)
#pragma unroll
                for (int j = 0; j < 4; ++j)
                    acc[i][j] = __builtin_amdgcn_mfma_f32_16x16x32_bf16(a[i], b[j], acc[i][j], 0, 0, 0);
        }
        __syncthreads();
    }

#pragma unroll
    for (int j = 0; j < 4; ++j) {
        int n = n0 + wn * 64 + j * 16 + fr;
        float bv = bias[n];
#pragma unroll
        for (int i = 0; i < 4; ++i) {
#pragma unroll
            for (int r = 0; r < 4; ++r) {
                int m = m0 + wm * 64 + i * 16 + kg * 4 + r;
                if (m < NN) {
                    float v = acc[i][j][r] + bv;
                    if (RELU) v = fmaxf(v, 0.f);
                    if (OUTF32) outf[(size_t)m * outld + n] = v;
                    else        outb[(size_t)m * outld + n] = f2bf(v);
                    if (OUTF8)
                        out8[(size_t)m * DOUT + n] =
                            (unsigned char)((uint)__builtin_amdgcn_cvt_pk_fp8_f32(v, v, 0, false) & 0xffu);
                }
            }
        }
    }
}

extern "C" void kernel_launch(void* const* d_in, const int* in_sizes, int n_in,
                              void* d_out, int out_size, void* d_ws, size_t ws_size,
                              hipStream_t stream) {
    const float* x     = (const float*)d_in[0];
    const int*   ei    = (const int*)d_in[1];
    const float* gamma = (const float*)d_in[2];
    const float* beta  = (const float*)d_in[3];
    const float* Wl1   = (const float*)d_in[4];
    const float* bl1   = (const float*)d_in[5];
    const float* Wr1   = (const float*)d_in[6];
    const float* Wl2   = (const float*)d_in[7];
    const float* bl2   = (const float*)d_in[8];
    const float* Wr2   = (const float*)d_in[9];
    const float* Wsr   = (const float*)d_in[10];
    const float* bs    = (const float*)d_in[11];
    float* out = (float*)d_out;

    const int* src = ei;
    const int* tgt = ei + NE;

    char* base = (char*)d_ws;
    size_t off = 0;
    auto alloc = [&](size_t bytes) -> void* {
        void* p = base + off;
        off += (bytes + 255) & ~(size_t)255;
        return p;
    };
    float*  colpart  = (float*)alloc(128 * 256 * sizeof(float));            // BN partials
    float*  bias1    = (float*)alloc(DOUT * sizeof(float));
    float*  biasc    = (float*)alloc(DOUT * sizeof(float));
    int*    nodecnt  = (int*)alloc(NN * sizeof(int));
    int*    boff     = (int*)alloc((size_t)NSB * (NBKT + 1) * sizeof(int));
    uint*   bsorted  = (uint*)alloc((size_t)NE * sizeof(uint));             // 2.56 MB
    ushort* csr      = (ushort*)alloc((size_t)MPAD * SLOTS_PN * sizeof(ushort)); // 3.2 MB
    ushort* cat1     = (ushort*)alloc((size_t)MPAD * 256 * sizeof(ushort)); // [x | agg_x]
    ushort* cat2     = (ushort*)alloc((size_t)MPAD * 640 * sizeof(ushort)); // [h1 | agg2 | x]
    ushort* wcat1    = (ushort*)alloc(256 * 256 * sizeof(ushort));          // [Wr1|Wl1]*scale
    ushort* wcat2    = (ushort*)alloc(256 * 640 * sizeof(ushort));          // [Wr2|Wl2|Ws]
    uint*   x8       = (uint*)alloc((size_t)MPAD * 128);                    // fp8 raw x
    unsigned char* h8 = (unsigned char*)alloc((size_t)MPAD * 256);          // fp8 h1

    // k1: sortA | BN partials | x conversions   (no memset needed anywhere)
    k_setup<<<B_CVT, 256, 0, stream>>>(x, src, tgt, colpart, bsorted, boff, cat1, cat2, x8);

    // k2: sortB | BN-folded weight prep | bias fold
    k_prep2<<<P_W2 + 1, 256, 0, stream>>>(bsorted, boff, csr, nodecnt, colpart, gamma, beta,
                                          Wl1, Wr1, Wl2, Wr2, Wsr, bl1, bl2, bs,
                                          wcat1, wcat2, bias1, biasc);

    dim3 ggrid((MPAD / 128), 2);

    // conv1: h1 = relu([x|agg_x] @ ([Wr1|Wl1]*scale)^T + bias1) -> bf16 cat2 0:256 + fp8 h8
    k_agg8<8, 8><<<NN / 4, 256, 0, stream>>>((const unsigned char*)x8, 8, nodecnt, csr,
                                             cat1, 16, 32);
    k_mm<256, true, false, true><<<ggrid, 256, 0, stream>>>(cat1, wcat1, bias1, nullptr,
                                                            cat2, 640, h8);

    // conv2 + residual: out = [h1|agg2|x] @ [Wr2|Wl2|Ws]^T + (bl2+bs)  (f32)
    k_agg8<16, 4><<<NN / 4, 256, 0, stream>>>(h8, 16, nodecnt, csr, cat2, 32, 80);
    k_mm<640, false, true, false><<<ggrid, 256, 0, stream>>>(cat2, wcat2, biasc, out,
                                                             nullptr, 256, nullptr);
}